// Round 4
// baseline (23182.825 us; speedup 1.0000x reference)
//
#include <hip/hip_runtime.h>
#include <math.h>

#define NB 128      // batch
#define NT 64       // timesteps
#define NI 512      // input dim
#define NH 1024     // hidden dim
#define NO 512      // output dim
#define PONDOFF (NB*NT*NO)

// s_h bank-deswizzle: pad each 128-float k-chunk by +4 so the 8 kq-slices
// (stride 132) start on distinct bank-quads -> the k-loop's 8-address b128
// broadcast read is conflict-free. Bijective k -> (k>>7)*132 + (k&127).
__device__ __forceinline__ int swz(int k) { return (k >> 7)*132 + (k & 127); }

// one-time transpose: whhT[k][j] = w_hh[j][k]  (4 MB in ws)
__global__ void prep_whhT(const float* __restrict__ w_hh, float* __restrict__ whhT)
{
    int e = blockIdx.x*blockDim.x + threadIdx.x;
    const int stride = gridDim.x*blockDim.x;
    for (; e < NH*NH; e += stride) {
        const int k = e >> 10, j = e & 1023;
        whhT[e] = w_hh[j*NH + k];
    }
}

// 64 independent blocks x 1024 threads; block owns batch rows 2*bid, 2*bid+1
// end-to-end. NO cross-block communication after prep: the h-recurrence,
// halting state machine, and epilogue are all block-local (one __syncthreads
// per step). All blocks read the same L2-resident weights (whhT/w_ih/w_out).
//
// Wave layout for the hh GEMV: wave wv = j-segment (64 cols), lane =
// (kq = lane>>3: 128-k slice) x (jp = lane&7: 8-col group). Each lane
// accumulates 8 cols x 2 rows over its k-slice; shfl_xor(8,16,32) folds the
// 8 kq partials -> every lane holds full dots for its 8 cols.
__global__ void __launch_bounds__(1024)
arnn_rows(const float* __restrict__ x, const float* __restrict__ s0,
          const float* __restrict__ w_ih, const float* __restrict__ whhT,
          const float* __restrict__ b_ih, const float* __restrict__ b_hh,
          const float* __restrict__ w_halt, const float* __restrict__ b_halt,
          const float* __restrict__ w_out, const float* __restrict__ b_out,
          float* __restrict__ out)
{
    const int tid  = threadIdx.x;
    const int b0   = blockIdx.x * 2;
    const int lane = tid & 63;
    const int wv   = tid >> 6;        // wave 0..15 = j-segment
    const int kq   = lane >> 3;       // 0..7  k-slice (128 k each)
    const int jp   = lane & 7;        // 0..7
    const int j0   = wv*64 + jp*8;    // my 8 output cols
    const int g    = tid >> 4;        // 0..63 (xw/epilogue group id)
    const int l16  = tid & 15;        // lane within group

    __shared__ float s_h[2*2*1056];   // [buf][row][swz(1024)] ping-pong h
    __shared__ float s_xw[2*NH];      // per-timestep x-part (+bias folded)
    __shared__ float s_whalt[NH];
    __shared__ float s_w0[NH];        // w_ih[:,0] (ones-column weight)
    __shared__ float s_bias[NH];      // b_ih + b_hh
    __shared__ float s_bout[NO];
    __shared__ float s_pred[2][16][2];// [step parity][wave][row] p partials

    s_whalt[tid] = w_halt[tid];
    s_w0[tid]    = w_ih[tid*(NI+1)];
    s_bias[tid]  = b_ih[tid] + b_hh[tid];
    if (tid < NO) s_bout[tid] = b_out[tid];
    // t=0 carry = s0
    s_h[swz(tid)]        = s0[(b0+0)*NH + tid];
    s_h[1056 + swz(tid)] = s0[(b0+1)*NH + tid];
    const float bh = b_halt[0];
    __syncthreads();

    int buf = 0;
    float cum0 = 0.f, cum1 = 0.f;
    int   en0 = 0, en1 = 0, act0 = 1, act1 = 1;

    for (int t = 0; t < NT; ++t) {
        // ========== x-part (once per timestep; shared by all ponder steps) ==========
        // group g (16 lanes) owns cols j = p*64+g; lane l16 owns i-slice of 32.
        {
            float xa0[16], xa1[16];
            #pragma unroll
            for (int p = 0; p < 16; ++p) { xa0[p] = 0.f; xa1[p] = 0.f; }
            const float* xr0 = x + ((b0+0)*NT + t)*NI + l16*32;
            const float* xr1 = x + ((b0+1)*NT + t)*NI + l16*32;
            for (int i2 = 0; i2 < 32; ++i2) {
                const float xv0 = xr0[i2];
                const float xv1 = xr1[i2];
                const int   ib  = l16*32 + i2;
                #pragma unroll
                for (int p = 0; p < 16; ++p) {
                    const float wvv = w_ih[(p*64 + g)*(NI+1) + 1 + ib];
                    xa0[p] += wvv*xv0;
                    xa1[p] += wvv*xv1;
                }
            }
            #pragma unroll
            for (int p = 0; p < 16; ++p) {
                xa0[p] += __shfl_xor(xa0[p], 1); xa0[p] += __shfl_xor(xa0[p], 2);
                xa0[p] += __shfl_xor(xa0[p], 4); xa0[p] += __shfl_xor(xa0[p], 8);
                xa1[p] += __shfl_xor(xa1[p], 1); xa1[p] += __shfl_xor(xa1[p], 2);
                xa1[p] += __shfl_xor(xa1[p], 4); xa1[p] += __shfl_xor(xa1[p], 8);
            }
            if (l16 == 0) {
                #pragma unroll
                for (int p = 0; p < 16; ++p) {
                    const int j = p*64 + g;
                    s_xw[j]      = xa0[p] + s_bias[j];
                    s_xw[NH + j] = xa1[p] + s_bias[j];
                }
            }
        }
        __syncthreads();

        // ========== step loop (main + up to 11 ponder) ==========
        float hacc0[8], hacc1[8];
        act0 = 1; act1 = 1;            // main step always executes
        int n = 0;
        for (;;) {
            const int ismain = (n == 0);
            // ---- hh GEMV over my 128-k slice ----
            float a0[8], a1[8];
            #pragma unroll
            for (int cc = 0; cc < 8; ++cc) { a0[cc] = 0.f; a1[cc] = 0.f; }
            const float* hb0 = &s_h[(buf*2 + 0)*1056 + kq*132];
            const float* hb1 = &s_h[(buf*2 + 1)*1056 + kq*132];
            const float* wb  = whhT + (kq*128)*NH + j0;
            #pragma unroll 2
            for (int it4 = 0; it4 < 32; ++it4) {
                const float4 hq0 = *(const float4*)(hb0 + it4*4);
                const float4 hq1 = *(const float4*)(hb1 + it4*4);
                const float h0c[4] = {hq0.x, hq0.y, hq0.z, hq0.w};
                const float h1c[4] = {hq1.x, hq1.y, hq1.z, hq1.w};
                #pragma unroll
                for (int c = 0; c < 4; ++c) {
                    const float4 wa  = *(const float4*)(wb + (it4*4 + c)*NH);
                    const float4 wb4 = *(const float4*)(wb + (it4*4 + c)*NH + 4);
                    const float wc8[8] = {wa.x, wa.y, wa.z, wa.w,
                                          wb4.x, wb4.y, wb4.z, wb4.w};
                    #pragma unroll
                    for (int cc = 0; cc < 8; ++cc) {
                        a0[cc] += wc8[cc]*h0c[c];
                        a1[cc] += wc8[cc]*h1c[c];
                    }
                }
            }
            // fold the 8 kq partials (lane bits 3..5) -> full dots, replicated
            #pragma unroll
            for (int cc = 0; cc < 8; ++cc) {
                a0[cc] += __shfl_xor(a0[cc], 8);
                a0[cc] += __shfl_xor(a0[cc], 16);
                a0[cc] += __shfl_xor(a0[cc], 32);
                a1[cc] += __shfl_xor(a1[cc], 8);
                a1[cc] += __shfl_xor(a1[cc], 16);
                a1[cc] += __shfl_xor(a1[cc], 32);
            }
            // ---- finalize h_new (active-masked), h_acc, p partials ----
            float hn0[8], hn1[8];
            float pp0 = 0.f, pp1 = 0.f;
            #pragma unroll
            for (int cc = 0; cc < 8; ++cc) {
                const int j = j0 + cc;
                float v0 = a0[cc] + s_xw[j];
                float v1 = a1[cc] + s_xw[NH + j];
                if (ismain) { v0 += s_w0[j]; v1 += s_w0[j]; }
                hn0[cc] = act0 ? tanhf(v0) : 0.0f;
                hn1[cc] = act1 ? tanhf(v1) : 0.0f;
                pp0 += s_whalt[j]*hn0[cc];
                pp1 += s_whalt[j]*hn1[cc];
                if (ismain) { hacc0[cc] = hn0[cc];  hacc1[cc] = hn1[cc]; }
                else        { hacc0[cc] += hn0[cc]; hacc1[cc] += hn1[cc]; }
            }
            // fold jp (bits 0..2): every lane -> wave sum (kq copies identical)
            pp0 += __shfl_xor(pp0, 1); pp0 += __shfl_xor(pp0, 2); pp0 += __shfl_xor(pp0, 4);
            pp1 += __shfl_xor(pp1, 1); pp1 += __shfl_xor(pp1, 2); pp1 += __shfl_xor(pp1, 4);
            if (lane == 0) { s_pred[n & 1][wv][0] = pp0; s_pred[n & 1][wv][1] = pp1; }
            // ---- publish h_new into the other buffer ----
            if (kq == 0) {
                const int nb_ = buf ^ 1;
                const int sa  = swz(j0);
                float* d0 = &s_h[(nb_*2 + 0)*1056];
                float* d1 = &s_h[(nb_*2 + 1)*1056];
                *(float4*)(d0 + sa)     = make_float4(hn0[0], hn0[1], hn0[2], hn0[3]);
                *(float4*)(d0 + sa + 4) = make_float4(hn0[4], hn0[5], hn0[6], hn0[7]);
                *(float4*)(d1 + sa)     = make_float4(hn1[0], hn1[1], hn1[2], hn1[3]);
                *(float4*)(d1 + sa + 4) = make_float4(hn1[4], hn1[5], hn1[6], hn1[7]);
            }
            __syncthreads();
            // ---- p finalize + state update (replicated, deterministic) ----
            float ps0 = 0.f, ps1 = 0.f;
            #pragma unroll
            for (int ww = 0; ww < 16; ++ww) {
                ps0 += s_pred[n & 1][ww][0];
                ps1 += s_pred[n & 1][ww][1];
            }
            const float p0 = act0 ? 1.0f/(1.0f + expf(-(ps0 + bh))) : 0.0f;
            const float p1 = act1 ? 1.0f/(1.0f + expf(-(ps1 + bh))) : 0.0f;
            if (ismain) {
                cum0 = p0; cum1 = p1; en0 = 1; en1 = 1;
                if (tid == 0) out[PONDOFF + (b0+0)*NT + t] = (p0 >= 0.99f) ? 2.0f : 0.0f;
                if (tid == 1) out[PONDOFF + (b0+1)*NT + t] = (p1 >= 0.99f) ? 2.0f : 0.0f;
            } else {
                en0 += act0; en1 += act1;   // counted for steps that were active
                cum0 += p0;  cum1 += p1;
            }
            act0 = (cum0 < 0.99f); act1 = (cum1 < 0.99f);
            buf ^= 1;
            ++n;
            if (n == 12 || !(act0 | act1)) break;
        }

        // ========== timestep end: carry = h_acc; epilogue ==========
        const int hb2 = buf ^ 1;
        if (kq == 0) {
            const int sa = swz(j0);
            float* d0 = &s_h[(hb2*2 + 0)*1056];
            float* d1 = &s_h[(hb2*2 + 1)*1056];
            *(float4*)(d0 + sa)     = make_float4(hacc0[0], hacc0[1], hacc0[2], hacc0[3]);
            *(float4*)(d0 + sa + 4) = make_float4(hacc0[4], hacc0[5], hacc0[6], hacc0[7]);
            *(float4*)(d1 + sa)     = make_float4(hacc1[0], hacc1[1], hacc1[2], hacc1[3]);
            *(float4*)(d1 + sa + 4) = make_float4(hacc1[4], hacc1[5], hacc1[6], hacc1[7]);
        }
        __syncthreads();
        // out[b,t,:] = w_out @ h_acc + n*b_out.  Group g: lane l16 owns a fixed
        // 64-j slice; loops its 8 o's per q so each h-read serves 8 outputs.
        {
            float e0[8], e1[8];
            #pragma unroll
            for (int p8 = 0; p8 < 8; ++p8) { e0[p8] = 0.f; e1[p8] = 0.f; }
            const float* hs0 = &s_h[(hb2*2 + 0)*1056];
            const float* hs1 = &s_h[(hb2*2 + 1)*1056];
            #pragma unroll 2
            for (int q = 0; q < 16; ++q) {
                const int jj = l16*64 + q*4;
                const int sa = swz(jj);
                const float4 hv0 = *(const float4*)(hs0 + sa);
                const float4 hv1 = *(const float4*)(hs1 + sa);
                #pragma unroll
                for (int p8 = 0; p8 < 8; ++p8) {
                    const float4 wq = *(const float4*)(w_out + (p8*64 + g)*NH + jj);
                    e0[p8] += wq.x*hv0.x + wq.y*hv0.y + wq.z*hv0.z + wq.w*hv0.w;
                    e1[p8] += wq.x*hv1.x + wq.y*hv1.y + wq.z*hv1.z + wq.w*hv1.w;
                }
            }
            #pragma unroll
            for (int p8 = 0; p8 < 8; ++p8) {
                e0[p8] += __shfl_xor(e0[p8], 1); e0[p8] += __shfl_xor(e0[p8], 2);
                e0[p8] += __shfl_xor(e0[p8], 4); e0[p8] += __shfl_xor(e0[p8], 8);
                e1[p8] += __shfl_xor(e1[p8], 1); e1[p8] += __shfl_xor(e1[p8], 2);
                e1[p8] += __shfl_xor(e1[p8], 4); e1[p8] += __shfl_xor(e1[p8], 8);
            }
            if (l16 == 0) {
                #pragma unroll
                for (int p8 = 0; p8 < 8; ++p8) {
                    const int o = p8*64 + g;
                    out[((b0+0)*NT + t)*NO + o] = e0[p8] + (float)en0*s_bout[o];
                    out[((b0+1)*NT + t)*NO + o] = e1[p8] + (float)en1*s_bout[o];
                }
            }
        }
        buf = hb2;   // carry (h_acc) is the next main step's h source
        // next timestep's post-xw __syncthreads guards epilogue stragglers
    }
}

extern "C" void kernel_launch(void* const* d_in, const int* in_sizes, int n_in,
                              void* d_out, int out_size, void* d_ws, size_t ws_size,
                              hipStream_t stream) {
    const float* x      = (const float*)d_in[0];
    const float* s0     = (const float*)d_in[1];
    const float* w_ih   = (const float*)d_in[2];
    const float* w_hh   = (const float*)d_in[3];
    const float* b_ih   = (const float*)d_in[4];
    const float* b_hh   = (const float*)d_in[5];
    const float* w_halt = (const float*)d_in[6];
    const float* b_halt = (const float*)d_in[7];
    const float* w_out  = (const float*)d_in[8];
    const float* b_out  = (const float*)d_in[9];
    float* out  = (float*)d_out;
    float* whhT = (float*)d_ws;     // 4 MB

    hipLaunchKernelGGL(prep_whhT, dim3(256), dim3(1024), 0, stream, w_hh, whhT);
    hipLaunchKernelGGL(arnn_rows, dim3(64), dim3(1024), 0, stream,
                       x, s0, w_ih, whhT, b_ih, b_hh, w_halt, b_halt,
                       w_out, b_out, out);
}

// Round 7
// 11775.896 us; speedup vs baseline: 1.9687x; 1.9687x over previous
//
#include <hip/hip_runtime.h>
#include <hip/hip_cooperative_groups.h>
#include <math.h>

namespace cg = cooperative_groups;

#define NB 128      // batch
#define NT 64       // timesteps
#define NI 512      // input dim
#define NH 1024     // hidden dim
#define NO 512      // output dim
#define PONDOFF (NB*NT*NO)

// dynamic LDS: [1024][32] w_hh column-slice, XOR-swizzled, 128 KB
extern __shared__ float smem[];

// ---- L3-coherence-point fast path (sc0 sc1) --------------------------------
// Plain pipelined VMEM ops with cache-bypass bits: always fresh at the L3
// coherence point (cross-XCD coherent), 16B wide, multiple outstanding,
// counted by vmcnt. Round 1 proved the no-fence protocol correct with the
// slow (__hip_atomic_*) encoding; this is the fast encoding. With ALL
// cross-block data on this path, the per-interval agent release(wbl2)/
// acquire(inv) fences — which tag-walk the whole 4MB L2 — are deleted, and
// L2 stays warm for wihT/x/w_out across the entire kernel.
__device__ __forceinline__ float4 ld4cc(const float* p) {
    float4 v;
    asm volatile("global_load_dwordx4 %0, %1, off sc0 sc1" : "=v"(v) : "v"(p));
    return v;   // NOT valid until a following WAITV
}
__device__ __forceinline__ float4 ld4nc(const float* p) {   // normal cached
    float4 v;
    asm volatile("global_load_dwordx4 %0, %1, off" : "=v"(v) : "v"(p));
    return v;
}
__device__ __forceinline__ void st2cc(float* p, float a, float b) {
    float2 v = make_float2(a, b);
    asm volatile("global_store_dwordx2 %0, %1, off sc0 sc1"
                 :: "v"(p), "v"(v) : "memory");
}
// Counted wait, rule-18 form: asm-volatile waitcnt (ordered against the
// volatile loads) + sched_barrier(0) so the scheduler cannot hoist the
// register-only consumers above the wait. No tied operands (unsupported).
#define WAITV(N) do {                                            \
    asm volatile("s_waitcnt vmcnt(" #N ")" ::: "memory");        \
    __builtin_amdgcn_sched_barrier(0);                           \
} while (0)
__device__ __forceinline__ void vdrain() {
    asm volatile("s_waitcnt vmcnt(0)" ::: "memory");
}

// Per-group (32-block) barrier, v7 — fence-free:
//  - producer side: all cross-block stores are sc0sc1 write-through; the
//    explicit vmcnt drain (+ __syncthreads) guarantees they are AT the L3
//    coherence point before the arrival increment is issued.
//  - arrival: RELAXED fetch_add (agent scope executes at L3). No release ->
//    no buffer_wbl2 L2 tag-walk.
//  - poll: one lane, relaxed agent atomic load (fresh at L3, no ownership).
//  - NO acquire fence: readers use sc0sc1 loads exclusively -> cannot see
//    stale caches. L2 (weights/x) is never invalidated.
__device__ __forceinline__ void group_barrier(unsigned* ctr, unsigned target, int tid)
{
    vdrain();
    __syncthreads();
    if (tid == 0) {
        __hip_atomic_fetch_add(ctr, 1u, __ATOMIC_RELAXED, __HIP_MEMORY_SCOPE_AGENT);
        while (__hip_atomic_load(ctr, __ATOMIC_RELAXED, __HIP_MEMORY_SCOPE_AGENT) < target)
            __builtin_amdgcn_s_sleep(1);
    }
    __syncthreads();
}

// 256 blocks x 1024 threads. 8 groups x 32 blocks; group owns 16 batch rows,
// block owns a 32-col slice. ASYNC ROW SCHEDULING: every interval, every
// unfinished row executes one step (main or ponder) at its OWN timestep.
// All 32 blocks replicate the (deterministic, bit-identical) decision state
// machine -> uniform control flow.
__global__ void __launch_bounds__(1024, 1)
arnn_coop(const float* __restrict__ x, const float* __restrict__ s0,
          const float* __restrict__ w_ih, const float* __restrict__ w_hh,
          const float* __restrict__ b_ih, const float* __restrict__ b_hh,
          const float* __restrict__ w_halt, const float* __restrict__ b_halt,
          const float* __restrict__ w_out, const float* __restrict__ b_out,
          float* __restrict__ out, float* __restrict__ ws)
{
    cg::grid_group grid = cg::this_grid();
    const int tid = threadIdx.x;
    const int bid = blockIdx.x;
    const int gid = bid * 1024 + tid;

    // ws layout (floats)
    float* wihT  = ws;                       // [NI][NH]
    float* hbuf  = wihT + NI*NH;             // [NB][2][NH] per-row ping-pong h
    float* habuf = hbuf + NB*2*NH;           // [2][NB][NH] timestep-parity h_acc
    unsigned* ctrA = (unsigned*)(habuf + 2*NB*NH);  // [8][32] arrival ctrs, 128B stride

    const int gp = bid >> 5, lb = bid & 31;

    __shared__ float s_whalt[NH + (NH/16)*4];        // padded, 5 KB
    __shared__ int   s_t[16];
    __shared__ float s_cum[16];
    __shared__ int   s_n[16];
    __shared__ int   s_et[16], s_en[16];
    __shared__ unsigned char s_sl[16];
    __shared__ unsigned char s_run[16];
    __shared__ unsigned char s_mode[16];
    __shared__ unsigned char s_epi[16];

    // ---- phase 0 ----
    for (int e = gid; e < NI*NH; e += 256*1024) {
        const int i = e >> 10, jj = e & 1023;
        wihT[e] = w_ih[jj*(NI+1) + 1 + i];
    }
    if (gid < 8*32)
        __hip_atomic_store(&ctrA[gid], 0u, __ATOMIC_RELAXED, __HIP_MEMORY_SCOPE_AGENT);
    // stage this block's w_hh column slice into LDS, XOR-swizzled:
    // element (k, j) at float offset k*32 + ((j>>1)^((k>>6)&15))*2 + (j&1)
    for (int e = tid; e < 1024*32; e += 1024) {
        const int k = e & 1023, jj = e >> 10;
        const float v = w_hh[(lb*32 + jj)*NH + k];
        const int su = (jj >> 1) ^ ((k >> 6) & 15);
        smem[k*32 + su*2 + (jj & 1)] = v;
    }
    {
        const int j = tid;
        s_whalt[j + ((j >> 4) << 2)] = w_halt[j];
    }
    if (tid < 16) {
        s_t[tid] = 0; s_cum[tid] = 0.0f; s_n[tid] = 0;
        s_et[tid] = 0; s_en[tid] = 0;
        s_sl[tid] = 0; s_run[tid] = 1; s_mode[tid] = 0; s_epi[tid] = 0;
    }
    grid.sync();

    unsigned* ctr = ctrA + gp*32;

    const int w    = tid >> 6;
    const int lane = tid & 63;
    const int rq   = w >> 2;                 // row quad 0..3
    const int co   = w & 3;                  // col octet 0..3
    const int up   = lane & 3;               // col pair in octet
    const int ks   = lane >> 2;              // k-slice 0..15 (64 wide)
    const int u    = co*4 + up;              // col pair in block 0..15
    const int jg   = lb*32 + u*2;            // global col (pair base)
    const int b0   = gp*16 + rq*4;           // first of my 4 matmul rows
    const bool k0  = (ks == 0);
    const int ldsb = ks*2048 + ((u ^ ks) << 1);

    const float bh  = b_halt[0];
    const float bias0 = k0 ? (b_ih[jg]   + b_hh[jg])   : 0.0f;
    const float bias1 = k0 ? (b_ih[jg+1] + b_hh[jg+1]) : 0.0f;
    const float w0a   = k0 ? w_ih[jg*(NI+1)]     : 0.0f;
    const float w0b   = k0 ? w_ih[(jg+1)*(NI+1)] : 0.0f;

    // epilogue mapping: wave = row, lane = (ocol 0..15, kquarter 0..3)
    const int   eo = lb*16 + (lane & 15);
    const int   eq = lane >> 4;
    const int   eb = gp*16 + w;
    const float bo = b_out[eo];

    // decision mini-dot: wave w owns row gp*16+w; fixed tree = identical bits
    auto decide_p = [&](int slot) -> float {
        const float* hr = hbuf + ((gp*16 + w)*2 + slot)*NH + lane*16;
        float4 hv0 = ld4cc(hr);
        float4 hv1 = ld4cc(hr + 4);
        float4 hv2 = ld4cc(hr + 8);
        float4 hv3 = ld4cc(hr + 12);
        WAITV(0);
        float d = 0.0f;
        {
            const float4 wv = *(const float4*)(&s_whalt[lane*20 + 0]);
            d += hv0.x*wv.x + hv0.y*wv.y + hv0.z*wv.z + hv0.w*wv.w;
        }
        {
            const float4 wv = *(const float4*)(&s_whalt[lane*20 + 4]);
            d += hv1.x*wv.x + hv1.y*wv.y + hv1.z*wv.z + hv1.w*wv.w;
        }
        {
            const float4 wv = *(const float4*)(&s_whalt[lane*20 + 8]);
            d += hv2.x*wv.x + hv2.y*wv.y + hv2.z*wv.z + hv2.w*wv.w;
        }
        {
            const float4 wv = *(const float4*)(&s_whalt[lane*20 + 12]);
            d += hv3.x*wv.x + hv3.y*wv.y + hv3.z*wv.z + hv3.w*wv.w;
        }
        d += __shfl_xor(d, 1);  d += __shfl_xor(d, 2);  d += __shfl_xor(d, 4);
        d += __shfl_xor(d, 8);  d += __shfl_xor(d, 16); d += __shfl_xor(d, 32);
        return 1.0f / (1.0f + expf(-(d + bh)));
    };

    float xw[4][2];                          // per-row x-part, persists over ponder
    float hacc[4][2];                        // per-(row,colpair) h_acc, k0 lanes own it

    unsigned gen = 0;
    for (;;) {
        // ================= compute phase =================
        // ---- epilogue for my decide-row, if pending (ring-3 counted-vmcnt) ----
        if (s_epi[w]) {
            const int et = s_et[w];
            const float* hap = habuf + (et&1)*(NB*NH) + eb*NH + eq*256;
            const float* wq  = w_out + eo*NH + eq*256;
            float acc = 0.0f;
            float4 eh[3][2], ew[3][2];
            vdrain();                         // start counted region clean
            #pragma unroll
            for (int G = 0; G < 3; ++G) {
                eh[G][0] = ld4cc(hap + G*8);
                eh[G][1] = ld4cc(hap + G*8 + 4);
                ew[G][0] = ld4nc(wq + G*8);
                ew[G][1] = ld4nc(wq + G*8 + 4);
            }
            #pragma unroll
            for (int G = 0; G < 32; ++G) {
                const int s = G % 3;
                if (G <= 29)      WAITV(8);
                else if (G == 30) WAITV(4);
                else              WAITV(0);
                acc += eh[s][0].x*ew[s][0].x + eh[s][0].y*ew[s][0].y
                     + eh[s][0].z*ew[s][0].z + eh[s][0].w*ew[s][0].w;
                acc += eh[s][1].x*ew[s][1].x + eh[s][1].y*ew[s][1].y
                     + eh[s][1].z*ew[s][1].z + eh[s][1].w*ew[s][1].w;
                if (G <= 28) {
                    eh[s][0] = ld4cc(hap + (G+3)*8);
                    eh[s][1] = ld4cc(hap + (G+3)*8 + 4);
                    ew[s][0] = ld4nc(wq + (G+3)*8);
                    ew[s][1] = ld4nc(wq + (G+3)*8 + 4);
                }
            }
            acc += __shfl_xor(acc, 16); acc += __shfl_xor(acc, 32);
            if (eq == 0) out[(eb*NT + et)*NO + eo] = acc + (float)s_en[w]*bo;
        }
        // ---- one step for each of my 4 matmul rows ----
        int ex[4], md[4], tt[4], sl[4];
        #pragma unroll
        for (int r = 0; r < 4; ++r) {
            const int rr = rq*4 + r;
            ex[r] = s_run[rr]; md[r] = s_mode[rr]; tt[r] = s_t[rr]; sl[r] = s_sl[rr];
        }
        if (ex[0] | ex[1] | ex[2] | ex[3]) {
            // x-part for rows starting a timestep (wave-uniform branches);
            // x / wihT are plain cached loads — L2 never invalidated -> warm
            #pragma unroll
            for (int r = 0; r < 4; ++r) {
                if (ex[r] && md[r] == 0) {
                    float o0 = bias0, o1 = bias1;
                    const float* xr = x + ((b0+r)*NT + tt[r])*NI + ks*32;
                    const float* wp = wihT + (ks*32)*NH + jg;
                    #pragma unroll 4
                    for (int i = 0; i < 32; i += 4) {
                        const float4 xv = *(const float4*)(xr + i);
                        const float2 wa = *(const float2*)(wp + (i  )*NH);
                        const float2 wb = *(const float2*)(wp + (i+1)*NH);
                        const float2 wc = *(const float2*)(wp + (i+2)*NH);
                        const float2 wd = *(const float2*)(wp + (i+3)*NH);
                        o0 += xv.x*wa.x + xv.y*wb.x + xv.z*wc.x + xv.w*wd.x;
                        o1 += xv.x*wa.y + xv.y*wb.y + xv.z*wc.y + xv.w*wd.y;
                    }
                    xw[r][0] = o0; xw[r][1] = o1;
                }
            }
            // hh matmul: per-row source by mode; dead rows compute garbage
            // (discarded). h = sc0sc1 loads, ring-3 pipelined (12 in flight).
            float a[4][2];
            const float* hp[4];
            #pragma unroll
            for (int r = 0; r < 4; ++r) {
                const int b = b0 + r;
                a[r][0] = xw[r][0] + (md[r] == 0 ? w0a : 0.0f);
                a[r][1] = xw[r][1] + (md[r] == 0 ? w0b : 0.0f);
                if (!ex[r])           hp[r] = hbuf + (b*2)*NH + ks*64;
                else if (md[r] == 0)  hp[r] = (tt[r] == 0 ? s0 + b*NH
                                              : habuf + ((tt[r]-1)&1)*(NB*NH) + b*NH) + ks*64;
                else                  hp[r] = hbuf + (b*2 + sl[r])*NH + ks*64;
            }
            vdrain();                         // start counted region clean
            float4 hr3[3][4];
            #pragma unroll
            for (int g = 0; g < 3; ++g) {
                #pragma unroll
                for (int r = 0; r < 4; ++r)
                    hr3[g][r] = ld4cc(hp[r] + g*4);
            }
            #pragma unroll
            for (int g = 0; g < 16; ++g) {
                const int s = g % 3;
                if (g <= 13)      WAITV(8);
                else if (g == 14) WAITV(4);
                else              WAITV(0);
                const float4 h0 = hr3[s][0];
                const float4 h1 = hr3[s][1];
                const float4 h2 = hr3[s][2];
                const float4 h3 = hr3[s][3];
                const int kc = g*4;
                const float2 wa = *(const float2*)(smem + ldsb + (kc  )*32);
                const float2 wb = *(const float2*)(smem + ldsb + (kc+1)*32);
                const float2 wc = *(const float2*)(smem + ldsb + (kc+2)*32);
                const float2 wd = *(const float2*)(smem + ldsb + (kc+3)*32);
                a[0][0] += h0.x*wa.x + h0.y*wb.x + h0.z*wc.x + h0.w*wd.x;
                a[0][1] += h0.x*wa.y + h0.y*wb.y + h0.z*wc.y + h0.w*wd.y;
                a[1][0] += h1.x*wa.x + h1.y*wb.x + h1.z*wc.x + h1.w*wd.x;
                a[1][1] += h1.x*wa.y + h1.y*wb.y + h1.z*wc.y + h1.w*wd.y;
                a[2][0] += h2.x*wa.x + h2.y*wb.x + h2.z*wc.x + h2.w*wd.x;
                a[2][1] += h2.x*wa.y + h2.y*wb.y + h2.z*wc.y + h2.w*wd.y;
                a[3][0] += h3.x*wa.x + h3.y*wb.x + h3.z*wc.x + h3.w*wd.x;
                a[3][1] += h3.x*wa.y + h3.y*wb.y + h3.z*wc.y + h3.w*wd.y;
                if (g <= 12) {
                    #pragma unroll
                    for (int r = 0; r < 4; ++r)
                        hr3[s][r] = ld4cc(hp[r] + (g+3)*4);
                }
            }
            #pragma unroll
            for (int r = 0; r < 4; ++r)
                #pragma unroll
                for (int c = 0; c < 2; ++c) {
                    float v = a[r][c];
                    v += __shfl_xor(v, 4);  v += __shfl_xor(v, 8);
                    v += __shfl_xor(v, 16); v += __shfl_xor(v, 32);
                    a[r][c] = v;
                }
            if (k0) {
                #pragma unroll
                for (int r = 0; r < 4; ++r) {
                    if (ex[r]) {
                        const float ha = tanhf(a[r][0]), hb = tanhf(a[r][1]);
                        const int b = b0 + r;
                        st2cc(hbuf + (b*2 + (sl[r]^1))*NH + jg, ha, hb);
                        // h_acc accumulates in registers (this lane is the sole
                        // owner of (b, jg)); publish for cross-block readers.
                        if (md[r] == 0) { hacc[r][0] = ha;  hacc[r][1] = hb; }
                        else            { hacc[r][0] += ha; hacc[r][1] += hb; }
                        st2cc(habuf + (tt[r]&1)*(NB*NH) + b*NH + jg,
                              hacc[r][0], hacc[r][1]);
                    }
                }
            }
        }
        // ================= barrier =================
        ++gen; group_barrier(ctr, 32*gen, tid);
        // ================= decide + state update (row w, bit-identical) ========
        const int exw = s_run[w];
        float p = 0.0f;
        if (exw) p = decide_p(s_sl[w] ^ 1);
        if (lane == 0) {
            int newepi = 0;
            if (exw) {
                const int t = s_t[w];
                float cum; int n;
                if (s_mode[w] == 0) {
                    cum = p; n = 1;
                    if (lb == 0) out[PONDOFF + (gp*16 + w)*NT + t] = (p >= 0.99f) ? 2.0f : 0.0f;
                } else {
                    cum = s_cum[w] + p; n = s_n[w] + 1;
                }
                s_cum[w] = cum; s_n[w] = n;
                s_sl[w] ^= 1;
                if ((cum < 0.99f) && n < 12) {
                    s_mode[w] = 1;
                } else {                     // timestep finished
                    newepi = 1; s_et[w] = t; s_en[w] = n;
                    if (t == NT-1) s_run[w] = 0;
                    else { s_t[w] = t + 1; s_mode[w] = 0; }
                }
            }
            s_epi[w] = newepi;
        }
        __syncthreads();
        // alive check: every wave computes it from LDS (uniform result)
        const int al = (lane < 16) ? (s_run[lane] | s_epi[lane]) : 0;
        if (__ballot(al) == 0ULL) break;
    }
}

extern "C" void kernel_launch(void* const* d_in, const int* in_sizes, int n_in,
                              void* d_out, int out_size, void* d_ws, size_t ws_size,
                              hipStream_t stream) {
    const float* x      = (const float*)d_in[0];
    const float* s0     = (const float*)d_in[1];
    const float* w_ih   = (const float*)d_in[2];
    const float* w_hh   = (const float*)d_in[3];
    const float* b_ih   = (const float*)d_in[4];
    const float* b_hh   = (const float*)d_in[5];
    const float* w_halt = (const float*)d_in[6];
    const float* b_halt = (const float*)d_in[7];
    const float* w_out  = (const float*)d_in[8];
    const float* b_out  = (const float*)d_in[9];
    float* out = (float*)d_out;
    float* ws  = (float*)d_ws;

    static const int kLds = 131072;
    (void)hipFuncSetAttribute((const void*)arnn_coop,
                              hipFuncAttributeMaxDynamicSharedMemorySize, kLds);

    void* args[] = { (void*)&x, (void*)&s0, (void*)&w_ih, (void*)&w_hh,
                     (void*)&b_ih, (void*)&b_hh, (void*)&w_halt, (void*)&b_halt,
                     (void*)&w_out, (void*)&b_out, (void*)&out, (void*)&ws };
    (void)hipLaunchCooperativeKernel((void*)arnn_coop, dim3(256), dim3(1024),
                                     args, kLds, stream);
}

// Round 8
// 9206.921 us; speedup vs baseline: 2.5180x; 1.2790x over previous
//
#include <hip/hip_runtime.h>
#include <hip/hip_cooperative_groups.h>
#include <math.h>

namespace cg = cooperative_groups;

#define NB 128      // batch
#define NT 64       // timesteps
#define NI 512      // input dim
#define NH 1024     // hidden dim
#define NO 512      // output dim
#define PONDOFF (NB*NT*NO)

// dynamic LDS: [1024][32] w_hh column-slice, XOR-swizzled, 128 KB
extern __shared__ float smem[];

// ---- L3-coherence-point path (sc0 sc1), used ONLY for cross-block h/p data.
__device__ __forceinline__ float4 ld4cc(const float* p) {
    float4 v;
    asm volatile("global_load_dwordx4 %0, %1, off sc0 sc1" : "=v"(v) : "v"(p));
    return v;   // NOT valid until a following WAITV
}
__device__ __forceinline__ float4 ld4nc(const float* p) {   // normal cached
    float4 v;
    asm volatile("global_load_dwordx4 %0, %1, off" : "=v"(v) : "v"(p));
    return v;
}
__device__ __forceinline__ void st2cc(float* p, float a, float b) {
    float2 v = make_float2(a, b);
    asm volatile("global_store_dwordx2 %0, %1, off sc0 sc1"
                 :: "v"(p), "v"(v) : "memory");
}
__device__ __forceinline__ void st1cc(float* p, float v) {
    asm volatile("global_store_dword %0, %1, off sc0 sc1"
                 :: "v"(p), "v"(v) : "memory");
}
#define WAITV(N) do {                                            \
    asm volatile("s_waitcnt vmcnt(" #N ")" ::: "memory");        \
    __builtin_amdgcn_sched_barrier(0);                           \
} while (0)
__device__ __forceinline__ void vdrain() {
    asm volatile("s_waitcnt vmcnt(0)" ::: "memory");
}

// Per-group (32-block) barrier — fence-free (proven r1/r7):
// sc0sc1 stores + vmcnt drain put data at the L3 coherence point before the
// relaxed arrival RMW; poll is a relaxed atomic load; readers use sc0sc1
// loads so no cache can serve stale h. L2 is NEVER invalidated -> wihT/x/
// w_out stay warm for the whole kernel.
__device__ __forceinline__ void group_barrier(unsigned* ctr, unsigned target, int tid)
{
    vdrain();
    __syncthreads();
    if (tid == 0) {
        __hip_atomic_fetch_add(ctr, 1u, __ATOMIC_RELAXED, __HIP_MEMORY_SCOPE_AGENT);
        while (__hip_atomic_load(ctr, __ATOMIC_RELAXED, __HIP_MEMORY_SCOPE_AGENT) < target)
            __builtin_amdgcn_s_sleep(1);
    }
    __syncthreads();
}

// 256 blocks x 1024 threads. 8 groups x 32 blocks; group owns 16 batch rows,
// block owns a 32-col slice of w_hh (in LDS). Per interval the block stages
// the group's h working set (16 rows x 4 KB) into LDS in 4 pipelined 16 KB
// passes (sc0sc1, deduplicated, bulk) and the hh matvec runs from LDS.
// Halting p is computed from per-block partial dots exchanged through pbuf
// and summed in a fixed tree (bit-identical across replicas).
__global__ void __launch_bounds__(1024, 1)
arnn_coop(const float* __restrict__ x, const float* __restrict__ s0,
          const float* __restrict__ w_ih, const float* __restrict__ w_hh,
          const float* __restrict__ b_ih, const float* __restrict__ b_hh,
          const float* __restrict__ w_halt, const float* __restrict__ b_halt,
          const float* __restrict__ w_out, const float* __restrict__ b_out,
          float* __restrict__ out, float* __restrict__ ws)
{
    cg::grid_group grid = cg::this_grid();
    const int tid = threadIdx.x;
    const int bid = blockIdx.x;
    const int gid = bid * 1024 + tid;

    // ws layout (floats)
    float* wihT  = ws;                       // [NI][NH]
    float* hbuf  = wihT + NI*NH;             // [NB][2][NH] per-row ping-pong h
    float* habuf = hbuf + NB*2*NH;           // [2][NB][NH] timestep-parity h_acc
    unsigned* ctrA = (unsigned*)(habuf + 2*NB*NH);  // [8][32] arrival ctrs
    float* pbuf  = (float*)(ctrA + 256);     // [8][16][32] halt-dot partials

    const int gp = bid >> 5, lb = bid & 31;

    __shared__ float s_hst[16*256];          // 16 KB staged h (one 16-k pass)
    __shared__ float s_pp[16][4];            // per-(row, co-wave) halt partials
    __shared__ int   s_t[16];
    __shared__ float s_cum[16];
    __shared__ int   s_n[16];
    __shared__ int   s_et[16], s_en[16];
    __shared__ unsigned char s_sl[16];
    __shared__ unsigned char s_run[16];
    __shared__ unsigned char s_mode[16];
    __shared__ unsigned char s_epi[16];

    // ---- phase 0 ----
    for (int e = gid; e < NI*NH; e += 256*1024) {
        const int i = e >> 10, jj = e & 1023;
        wihT[e] = w_ih[jj*(NI+1) + 1 + i];
    }
    if (gid < 256)
        __hip_atomic_store(&ctrA[gid], 0u, __ATOMIC_RELAXED, __HIP_MEMORY_SCOPE_AGENT);
    // stage this block's w_hh column slice into LDS, XOR-swizzled:
    // element (k, j) at float offset k*32 + ((j>>1)^((k>>6)&15))*2 + (j&1)
    for (int e = tid; e < 1024*32; e += 1024) {
        const int k = e & 1023, jj = e >> 10;
        const float v = w_hh[(lb*32 + jj)*NH + k];
        const int su = (jj >> 1) ^ ((k >> 6) & 15);
        smem[k*32 + su*2 + (jj & 1)] = v;
    }
    if (tid < 16) {
        s_t[tid] = 0; s_cum[tid] = 0.0f; s_n[tid] = 0;
        s_et[tid] = 0; s_en[tid] = 0;
        s_sl[tid] = 0; s_run[tid] = 1; s_mode[tid] = 0; s_epi[tid] = 0;
    }
    grid.sync();

    unsigned* ctr = ctrA + gp*32;

    const int w    = tid >> 6;
    const int lane = tid & 63;
    const int rq   = w >> 2;                 // row quad 0..3
    const int co   = w & 3;                  // col octet 0..3
    const int up   = lane & 3;               // col pair in octet
    const int ks   = lane >> 2;              // k-slice 0..15 (64 wide)
    const int u    = co*4 + up;              // col pair in block 0..15
    const int jg   = lb*32 + u*2;            // global col (pair base)
    const int b0   = gp*16 + rq*4;           // first of my 4 matmul rows
    const bool k0  = (ks == 0);
    const int ldsb = ks*2048 + ((u ^ ks) << 1);

    const float bh  = b_halt[0];
    const float bias0 = k0 ? (b_ih[jg]   + b_hh[jg])   : 0.0f;
    const float bias1 = k0 ? (b_ih[jg+1] + b_hh[jg+1]) : 0.0f;
    const float w0a   = k0 ? w_ih[jg*(NI+1)]     : 0.0f;
    const float w0b   = k0 ? w_ih[(jg+1)*(NI+1)] : 0.0f;
    const float wh0   = w_halt[jg];
    const float wh1   = w_halt[jg+1];

    // epilogue mapping: wave = row, lane = (ocol 0..15, kquarter 0..3)
    const int   eo = lb*16 + (lane & 15);
    const int   eq = lane >> 4;
    const int   eb = gp*16 + w;
    const float bo = b_out[eo];

    // staging mapping: thread stages one float4 per pass for row tid>>6
    const int row_s = tid >> 6;              // group row 0..15
    const int q_s   = tid & 63;              // f4 index within 256-float chunk
    const int m_s   = q_s >> 2;              // 16 64-float k-slices
    const int t4_s  = q_s & 3;
    const int dstoff = row_s*256 + (q_s ^ (m_s & 7))*4;  // XOR-swizzled dest

    float xw[4][2];                          // per-row x-part, persists over ponder
    float hacc[4][2];                        // per-(row,colpair) h_acc, k0 lanes own it
    float a[4][2];

    // consume one 16-k pass from staged LDS; FP order identical to the r3
    // kernel's g-loop (k = ks*64 + g*4 + c with g = p*4 + j).
    auto consume = [&](int p) {
        #pragma unroll
        for (int j = 0; j < 4; ++j) {
            const int kc = p*16 + j*4;
            const float2 wa = *(const float2*)(smem + ldsb + (kc  )*32);
            const float2 wb = *(const float2*)(smem + ldsb + (kc+1)*32);
            const float2 wc = *(const float2*)(smem + ldsb + (kc+2)*32);
            const float2 wd = *(const float2*)(smem + ldsb + (kc+3)*32);
            const int Qs = ((ks*4 + j) ^ (ks & 7))*4;
            const float4 h0 = *(const float4*)(&s_hst[(rq*4+0)*256 + Qs]);
            const float4 h1 = *(const float4*)(&s_hst[(rq*4+1)*256 + Qs]);
            const float4 h2 = *(const float4*)(&s_hst[(rq*4+2)*256 + Qs]);
            const float4 h3 = *(const float4*)(&s_hst[(rq*4+3)*256 + Qs]);
            a[0][0] += h0.x*wa.x + h0.y*wb.x + h0.z*wc.x + h0.w*wd.x;
            a[0][1] += h0.x*wa.y + h0.y*wb.y + h0.z*wc.y + h0.w*wd.y;
            a[1][0] += h1.x*wa.x + h1.y*wb.x + h1.z*wc.x + h1.w*wd.x;
            a[1][1] += h1.x*wa.y + h1.y*wb.y + h1.z*wc.y + h1.w*wd.y;
            a[2][0] += h2.x*wa.x + h2.y*wb.x + h2.z*wc.x + h2.w*wd.x;
            a[2][1] += h2.x*wa.y + h2.y*wb.y + h2.z*wc.y + h2.w*wd.y;
            a[3][0] += h3.x*wa.x + h3.y*wb.x + h3.z*wc.x + h3.w*wd.x;
            a[3][1] += h3.x*wa.y + h3.y*wb.y + h3.z*wc.y + h3.w*wd.y;
        }
    };

    unsigned gen = 0;
    for (;;) {
        // ================= compute phase =================
        // ---- epilogue for my decide-row, if pending (ring-3 counted-vmcnt) ----
        if (s_epi[w]) {
            const int et = s_et[w];
            const float* hap = habuf + (et&1)*(NB*NH) + eb*NH + eq*256;
            const float* wq  = w_out + eo*NH + eq*256;
            float acc = 0.0f;
            float4 eh[3][2], ew[3][2];
            vdrain();
            #pragma unroll
            for (int G = 0; G < 3; ++G) {
                eh[G][0] = ld4cc(hap + G*8);
                eh[G][1] = ld4cc(hap + G*8 + 4);
                ew[G][0] = ld4nc(wq + G*8);
                ew[G][1] = ld4nc(wq + G*8 + 4);
            }
            #pragma unroll
            for (int G = 0; G < 32; ++G) {
                const int s = G % 3;
                if (G <= 29)      WAITV(8);
                else if (G == 30) WAITV(4);
                else              WAITV(0);
                acc += eh[s][0].x*ew[s][0].x + eh[s][0].y*ew[s][0].y
                     + eh[s][0].z*ew[s][0].z + eh[s][0].w*ew[s][0].w;
                acc += eh[s][1].x*ew[s][1].x + eh[s][1].y*ew[s][1].y
                     + eh[s][1].z*ew[s][1].z + eh[s][1].w*ew[s][1].w;
                if (G <= 28) {
                    eh[s][0] = ld4cc(hap + (G+3)*8);
                    eh[s][1] = ld4cc(hap + (G+3)*8 + 4);
                    ew[s][0] = ld4nc(wq + (G+3)*8);
                    ew[s][1] = ld4nc(wq + (G+3)*8 + 4);
                }
            }
            acc += __shfl_xor(acc, 16); acc += __shfl_xor(acc, 32);
            if (eq == 0) out[(eb*NT + et)*NO + eo] = acc + (float)s_en[w]*bo;
        }
        // ---- per-quad state ----
        int ex[4], md[4], tt[4], sl[4];
        #pragma unroll
        for (int r = 0; r < 4; ++r) {
            const int rr = rq*4 + r;
            ex[r] = s_run[rr]; md[r] = s_mode[rr]; tt[r] = s_t[rr]; sl[r] = s_sl[rr];
        }
        // ---- x-part for rows starting a timestep (L2-warm wihT/x) ----
        #pragma unroll
        for (int r = 0; r < 4; ++r) {
            if (ex[r] && md[r] == 0) {
                float o0 = bias0, o1 = bias1;
                const float* xr = x + ((b0+r)*NT + tt[r])*NI + ks*32;
                const float* wp = wihT + (ks*32)*NH + jg;
                #pragma unroll 4
                for (int i = 0; i < 32; i += 4) {
                    const float4 xv = *(const float4*)(xr + i);
                    const float2 wa = *(const float2*)(wp + (i  )*NH);
                    const float2 wb = *(const float2*)(wp + (i+1)*NH);
                    const float2 wc = *(const float2*)(wp + (i+2)*NH);
                    const float2 wd = *(const float2*)(wp + (i+3)*NH);
                    o0 += xv.x*wa.x + xv.y*wb.x + xv.z*wc.x + xv.w*wd.x;
                    o1 += xv.x*wa.y + xv.y*wb.y + xv.z*wc.y + xv.w*wd.y;
                }
                xw[r][0] = o0; xw[r][1] = o1;
            }
        }
        // ---- staging source for my staged row (replicated state -> uniform) ----
        const float* hsrc;
        {
            const int rn = s_run[row_s], rm = s_mode[row_s];
            const int rt = s_t[row_s],  rs = s_sl[row_s];
            const int b  = gp*16 + row_s;
            if (!rn)           hsrc = hbuf + (b*2)*NH;
            else if (rm == 0)  hsrc = (rt == 0) ? s0 + b*NH
                                      : habuf + ((rt-1)&1)*(NB*NH) + b*NH;
            else               hsrc = hbuf + (b*2 + rs)*NH;
        }
        const float* gbase = hsrc + m_s*64 + t4_s*4;
        // ---- a[] init ----
        #pragma unroll
        for (int r = 0; r < 4; ++r) {
            a[r][0] = xw[r][0] + (md[r] == 0 ? w0a : 0.0f);
            a[r][1] = xw[r][1] + (md[r] == 0 ? w0b : 0.0f);
        }
        // ---- 4-pass staged hh matvec (pipelined: load p+1 under consume p) ----
        vdrain();
        float4 fA = ld4cc(gbase);
        float4 fB;
        // pass 0
        WAITV(0); __syncthreads();
        *(float4*)(&s_hst[dstoff]) = fA;
        fB = ld4cc(gbase + 16);
        __syncthreads();
        consume(0);
        // pass 1
        WAITV(0); __syncthreads();
        *(float4*)(&s_hst[dstoff]) = fB;
        fA = ld4cc(gbase + 32);
        __syncthreads();
        consume(1);
        // pass 2
        WAITV(0); __syncthreads();
        *(float4*)(&s_hst[dstoff]) = fA;
        fB = ld4cc(gbase + 48);
        __syncthreads();
        consume(2);
        // pass 3
        WAITV(0); __syncthreads();
        *(float4*)(&s_hst[dstoff]) = fB;
        __syncthreads();
        consume(3);
        // ---- fold: every lane gets full dots for its col pair ----
        #pragma unroll
        for (int r = 0; r < 4; ++r)
            #pragma unroll
            for (int c = 0; c < 2; ++c) {
                float v = a[r][c];
                v += __shfl_xor(v, 4);  v += __shfl_xor(v, 8);
                v += __shfl_xor(v, 16); v += __shfl_xor(v, 32);
                a[r][c] = v;
            }
        // ---- k0 lanes: tanh, publish h, halt-dot partials ----
        if (k0) {
            #pragma unroll
            for (int r = 0; r < 4; ++r) {
                float ph = 0.0f;
                if (ex[r]) {
                    const float ha = tanhf(a[r][0]), hb = tanhf(a[r][1]);
                    const int b = b0 + r;
                    st2cc(hbuf + (b*2 + (sl[r]^1))*NH + jg, ha, hb);
                    if (md[r] == 0) { hacc[r][0] = ha;  hacc[r][1] = hb; }
                    else            { hacc[r][0] += ha; hacc[r][1] += hb; }
                    st2cc(habuf + (tt[r]&1)*(NB*NH) + b*NH + jg,
                          hacc[r][0], hacc[r][1]);
                    ph = wh0*ha + wh1*hb;
                }
                // fold the 4 up-lanes (0..3) -> wave's 8-col partial
                ph += __shfl_xor(ph, 1);
                ph += __shfl_xor(ph, 2);
                if (up == 0) s_pp[rq*4 + r][co] = ph;
            }
        }
        __syncthreads();
        // one lane per row: block's 32-col partial -> pbuf (fixed order)
        if (lane == 0) {
            const float s4 = ((s_pp[w][0] + s_pp[w][1]) + s_pp[w][2]) + s_pp[w][3];
            st1cc(pbuf + (gp*16 + w)*32 + lb, s4);
        }
        // ================= barrier =================
        ++gen; group_barrier(ctr, 32*gen, tid);
        // ====== p from partials (fixed tree, bit-identical across blocks) ======
        const int exw = s_run[w];
        float p = 0.0f;
        {
            const float* pb = pbuf + (gp*16 + w)*32 + (lane & 7)*4;
            float4 pv = ld4cc(pb);
            WAITV(0);
            float ps = ((pv.x + pv.y) + pv.z) + pv.w;
            ps += __shfl_xor(ps, 1);
            ps += __shfl_xor(ps, 2);
            ps += __shfl_xor(ps, 4);
            if (exw) p = 1.0f/(1.0f + expf(-(ps + bh)));
        }
        // ====== state update (row w, lane 0, replicated deterministic) ======
        if (lane == 0) {
            int newepi = 0;
            if (exw) {
                const int t = s_t[w];
                float cum; int n;
                if (s_mode[w] == 0) {
                    cum = p; n = 1;
                    if (lb == 0) out[PONDOFF + (gp*16 + w)*NT + t] = (p >= 0.99f) ? 2.0f : 0.0f;
                } else {
                    cum = s_cum[w] + p; n = s_n[w] + 1;
                }
                s_cum[w] = cum; s_n[w] = n;
                s_sl[w] ^= 1;
                if ((cum < 0.99f) && n < 12) {
                    s_mode[w] = 1;
                } else {                     // timestep finished
                    newepi = 1; s_et[w] = t; s_en[w] = n;
                    if (t == NT-1) s_run[w] = 0;
                    else { s_t[w] = t + 1; s_mode[w] = 0; }
                }
            }
            s_epi[w] = newepi;
        }
        __syncthreads();
        // alive check: every wave computes it from LDS (uniform result)
        const int al = (lane < 16) ? (s_run[lane] | s_epi[lane]) : 0;
        if (__ballot(al) == 0ULL) break;
    }
}

extern "C" void kernel_launch(void* const* d_in, const int* in_sizes, int n_in,
                              void* d_out, int out_size, void* d_ws, size_t ws_size,
                              hipStream_t stream) {
    const float* x      = (const float*)d_in[0];
    const float* s0     = (const float*)d_in[1];
    const float* w_ih   = (const float*)d_in[2];
    const float* w_hh   = (const float*)d_in[3];
    const float* b_ih   = (const float*)d_in[4];
    const float* b_hh   = (const float*)d_in[5];
    const float* w_halt = (const float*)d_in[6];
    const float* b_halt = (const float*)d_in[7];
    const float* w_out  = (const float*)d_in[8];
    const float* b_out  = (const float*)d_in[9];
    float* out = (float*)d_out;
    float* ws  = (float*)d_ws;

    static const int kLds = 131072;
    (void)hipFuncSetAttribute((const void*)arnn_coop,
                              hipFuncAttributeMaxDynamicSharedMemorySize, kLds);

    void* args[] = { (void*)&x, (void*)&s0, (void*)&w_ih, (void*)&w_hh,
                     (void*)&b_ih, (void*)&b_hh, (void*)&w_halt, (void*)&b_halt,
                     (void*)&w_out, (void*)&b_out, (void*)&out, (void*)&ws };
    (void)hipLaunchCooperativeKernel((void*)arnn_coop, dim3(256), dim3(1024),
                                     args, kLds, stream);
}

// Round 11
// 9148.107 us; speedup vs baseline: 2.5342x; 1.0064x over previous
//
#include <hip/hip_runtime.h>
#include <hip/hip_cooperative_groups.h>
#include <math.h>

namespace cg = cooperative_groups;

#define NB 128      // batch
#define NT 64       // timesteps
#define NI 512      // input dim
#define NH 1024     // hidden dim
#define NO 512      // output dim
#define PONDOFF (NB*NT*NO)

// dynamic LDS: [1024][32] w_hh column-slice, XOR-swizzled, 128 KB
extern __shared__ float smem[];

// ---- L3-coherence-point path (sc0 sc1), used ONLY for cross-block h/p data.
__device__ __forceinline__ float4 ld4cc(const float* p) {
    float4 v;
    asm volatile("global_load_dwordx4 %0, %1, off sc0 sc1" : "=v"(v) : "v"(p));
    return v;   // NOT valid until a following WAITV
}
__device__ __forceinline__ float4 ld4nc(const float* p) {   // normal cached
    float4 v;
    asm volatile("global_load_dwordx4 %0, %1, off" : "=v"(v) : "v"(p));
    return v;
}
__device__ __forceinline__ void st2cc(float* p, float a, float b) {
    float2 v = make_float2(a, b);
    asm volatile("global_store_dwordx2 %0, %1, off sc0 sc1"
                 :: "v"(p), "v"(v) : "memory");
}
__device__ __forceinline__ void st1cc(float* p, float v) {
    asm volatile("global_store_dword %0, %1, off sc0 sc1"
                 :: "v"(p), "v"(v) : "memory");
}
__device__ __forceinline__ void st1u(unsigned* p, unsigned v) {
    asm volatile("global_store_dword %0, %1, off sc0 sc1"
                 :: "v"(p), "v"(v) : "memory");
}
__device__ __forceinline__ unsigned ld1cc(const unsigned* p) {
    unsigned v;
    asm volatile("global_load_dword %0, %1, off sc0 sc1\n\ts_waitcnt vmcnt(0)"
                 : "=v"(v) : "v"(p) : "memory");
    return v;
}
#define WAITV(N) do {                                            \
    asm volatile("s_waitcnt vmcnt(" #N ")" ::: "memory");        \
    __builtin_amdgcn_sched_barrier(0);                           \
} while (0)
__device__ __forceinline__ void vdrain() {
    asm volatile("s_waitcnt vmcnt(0)" ::: "memory");
}

// Per-group (32-block) barrier, v9 — RMW-FREE, fence-free:
//  - producer side: all cross-block stores are sc0sc1 write-through; vdrain
//    (+ __syncthreads) puts them AT the L3 coherence point before arrival.
//  - arrival: ONE sc0sc1 STORE of `gen` into slots[lb]. Fire-and-forget —
//    no line-ownership transfer, so 32 arrivals proceed in parallel instead
//    of forming the serialized RMW queue of the fetch_add barrier (r8).
//  - detection: wave 0, lanes 0..31 each load one slot (parallel, one L3
//    round trip per poll iteration) + __all(v >= gen).
//  - NO acquire fence: readers use sc0sc1 loads exclusively. L2 is never
//    invalidated -> wihT/x/w_out stay warm for the whole kernel.
__device__ __forceinline__ void group_barrier(unsigned* slots, unsigned gen,
                                              int lb, int tid)
{
    vdrain();
    __syncthreads();
    if (tid < 64) {
        if (tid == 0) st1u(slots + lb, gen);
        unsigned v = gen;
        for (;;) {
            if (tid < 32) v = ld1cc(slots + tid);
            if (__all(v >= gen)) break;
            __builtin_amdgcn_s_sleep(2);
        }
    }
    __syncthreads();
}

// 256 blocks x 1024 threads. 8 groups x 32 blocks; group owns 16 batch rows,
// block owns a 32-col slice of w_hh (in LDS). Per interval the block stages
// the group's h working set (16 rows x 4 KB) into LDS in 4 pipelined 16 KB
// passes (sc0sc1, deduplicated, bulk) and the hh matvec runs from LDS.
// Halting p is computed from per-block partial dots exchanged through pbuf
// and summed in a fixed tree (bit-identical across replicas).
__global__ void __launch_bounds__(1024, 1)
arnn_coop(const float* __restrict__ x, const float* __restrict__ s0,
          const float* __restrict__ w_ih, const float* __restrict__ w_hh,
          const float* __restrict__ b_ih, const float* __restrict__ b_hh,
          const float* __restrict__ w_halt, const float* __restrict__ b_halt,
          const float* __restrict__ w_out, const float* __restrict__ b_out,
          float* __restrict__ out, float* __restrict__ ws)
{
    cg::grid_group grid = cg::this_grid();
    const int tid = threadIdx.x;
    const int bid = blockIdx.x;
    const int gid = bid * 1024 + tid;

    // ws layout (floats)
    float* wihT  = ws;                       // [NI][NH]
    float* hbuf  = wihT + NI*NH;             // [NB][2][NH] per-row ping-pong h
    float* habuf = hbuf + NB*2*NH;           // [2][NB][NH] timestep-parity h_acc
    unsigned* ctrA = (unsigned*)(habuf + 2*NB*NH);  // [8][32] barrier slots
    float* pbuf  = (float*)(ctrA + 256);     // [8][16][32] halt-dot partials

    const int gp = bid >> 5, lb = bid & 31;

    __shared__ float s_hst[16*256];          // 16 KB staged h (one 16-k pass)
    __shared__ float s_pp[16][4];            // per-(row, co-wave) halt partials
    __shared__ int   s_t[16];
    __shared__ float s_cum[16];
    __shared__ int   s_n[16];
    __shared__ int   s_et[16], s_en[16];
    __shared__ unsigned char s_sl[16];
    __shared__ unsigned char s_run[16];
    __shared__ unsigned char s_mode[16];
    __shared__ unsigned char s_epi[16];

    // ---- phase 0 ----
    for (int e = gid; e < NI*NH; e += 256*1024) {
        const int i = e >> 10, jj = e & 1023;
        wihT[e] = w_ih[jj*(NI+1) + 1 + i];
    }
    if (gid < 256)
        __hip_atomic_store(&ctrA[gid], 0u, __ATOMIC_RELAXED, __HIP_MEMORY_SCOPE_AGENT);
    // stage this block's w_hh column slice into LDS, XOR-swizzled:
    // element (k, j) at float offset k*32 + ((j>>1)^((k>>6)&15))*2 + (j&1)
    for (int e = tid; e < 1024*32; e += 1024) {
        const int k = e & 1023, jj = e >> 10;
        const float v = w_hh[(lb*32 + jj)*NH + k];
        const int su = (jj >> 1) ^ ((k >> 6) & 15);
        smem[k*32 + su*2 + (jj & 1)] = v;
    }
    if (tid < 16) {
        s_t[tid] = 0; s_cum[tid] = 0.0f; s_n[tid] = 0;
        s_et[tid] = 0; s_en[tid] = 0;
        s_sl[tid] = 0; s_run[tid] = 1; s_mode[tid] = 0; s_epi[tid] = 0;
    }
    grid.sync();

    unsigned* ctr = ctrA + gp*32;

    const int w    = tid >> 6;
    const int lane = tid & 63;
    const int rq   = w >> 2;                 // row quad 0..3
    const int co   = w & 3;                  // col octet 0..3
    const int up   = lane & 3;               // col pair in octet
    const int ks   = lane >> 2;              // k-slice 0..15 (64 wide)
    const int u    = co*4 + up;              // col pair in block 0..15
    const int jg   = lb*32 + u*2;            // global col (pair base)
    const int b0   = gp*16 + rq*4;           // first of my 4 matmul rows
    const bool k0  = (ks == 0);
    const int ldsb = ks*2048 + ((u ^ ks) << 1);

    const float bh  = b_halt[0];
    const float bias0 = k0 ? (b_ih[jg]   + b_hh[jg])   : 0.0f;
    const float bias1 = k0 ? (b_ih[jg+1] + b_hh[jg+1]) : 0.0f;
    const float w0a   = k0 ? w_ih[jg*(NI+1)]     : 0.0f;
    const float w0b   = k0 ? w_ih[(jg+1)*(NI+1)] : 0.0f;
    const float wh0   = k0 ? w_halt[jg]   : 0.0f;
    const float wh1   = k0 ? w_halt[jg+1] : 0.0f;

    // epilogue mapping: wave = row, lane = (ocol 0..15, kquarter 0..3)
    const int   eo = lb*16 + (lane & 15);
    const int   eq = lane >> 4;
    const int   eb = gp*16 + w;
    const float bo = b_out[eo];

    // staging mapping: thread stages one float4 per pass for row tid>>6
    const int row_s = tid >> 6;              // group row 0..15
    const int q_s   = tid & 63;              // f4 index within 256-float chunk
    const int m_s   = q_s >> 2;              // 16 64-float k-slices
    const int t4_s  = q_s & 3;
    const int dstoff = row_s*256 + (q_s ^ (m_s & 7))*4;  // XOR-swizzled dest

    float xw[4][2];                          // per-row x-part, persists over ponder
    float hacc[4][2];                        // per-(row,colpair) h_acc, k0 lanes own it
    float a[4][2];

    // consume one 16-k pass from staged LDS; FP order identical to the r3
    // kernel's g-loop (k = ks*64 + g*4 + c with g = p*4 + j).
    auto consume = [&](int p) {
        #pragma unroll
        for (int j = 0; j < 4; ++j) {
            const int kc = p*16 + j*4;
            const float2 wa = *(const float2*)(smem + ldsb + (kc  )*32);
            const float2 wb = *(const float2*)(smem + ldsb + (kc+1)*32);
            const float2 wc = *(const float2*)(smem + ldsb + (kc+2)*32);
            const float2 wd = *(const float2*)(smem + ldsb + (kc+3)*32);
            const int Qs = ((ks*4 + j) ^ (ks & 7))*4;
            const float4 h0 = *(const float4*)(&s_hst[(rq*4+0)*256 + Qs]);
            const float4 h1 = *(const float4*)(&s_hst[(rq*4+1)*256 + Qs]);
            const float4 h2 = *(const float4*)(&s_hst[(rq*4+2)*256 + Qs]);
            const float4 h3 = *(const float4*)(&s_hst[(rq*4+3)*256 + Qs]);
            a[0][0] += h0.x*wa.x + h0.y*wb.x + h0.z*wc.x + h0.w*wd.x;
            a[0][1] += h0.x*wa.y + h0.y*wb.y + h0.z*wc.y + h0.w*wd.y;
            a[1][0] += h1.x*wa.x + h1.y*wb.x + h1.z*wc.x + h1.w*wd.x;
            a[1][1] += h1.x*wa.y + h1.y*wb.y + h1.z*wc.y + h1.w*wd.y;
            a[2][0] += h2.x*wa.x + h2.y*wb.x + h2.z*wc.x + h2.w*wd.x;
            a[2][1] += h2.x*wa.y + h2.y*wb.y + h2.z*wc.y + h2.w*wd.y;
            a[3][0] += h3.x*wa.x + h3.y*wb.x + h3.z*wc.x + h3.w*wd.x;
            a[3][1] += h3.x*wa.y + h3.y*wb.y + h3.z*wc.y + h3.w*wd.y;
        }
    };

    unsigned gen = 0;
    for (;;) {
        // ================= compute phase =================
        // ---- epilogue for my decide-row, if pending (ring-3 counted-vmcnt) ----
        if (s_epi[w]) {
            const int et = s_et[w];
            const float* hap = habuf + (et&1)*(NB*NH) + eb*NH + eq*256;
            const float* wq  = w_out + eo*NH + eq*256;
            float acc = 0.0f;
            float4 eh[3][2], ew[3][2];
            vdrain();
            #pragma unroll
            for (int G = 0; G < 3; ++G) {
                eh[G][0] = ld4cc(hap + G*8);
                eh[G][1] = ld4cc(hap + G*8 + 4);
                ew[G][0] = ld4nc(wq + G*8);
                ew[G][1] = ld4nc(wq + G*8 + 4);
            }
            #pragma unroll
            for (int G = 0; G < 32; ++G) {
                const int s = G % 3;
                if (G <= 29)      WAITV(8);
                else if (G == 30) WAITV(4);
                else              WAITV(0);
                acc += eh[s][0].x*ew[s][0].x + eh[s][0].y*ew[s][0].y
                     + eh[s][0].z*ew[s][0].z + eh[s][0].w*ew[s][0].w;
                acc += eh[s][1].x*ew[s][1].x + eh[s][1].y*ew[s][1].y
                     + eh[s][1].z*ew[s][1].z + eh[s][1].w*ew[s][1].w;
                if (G <= 28) {
                    eh[s][0] = ld4cc(hap + (G+3)*8);
                    eh[s][1] = ld4cc(hap + (G+3)*8 + 4);
                    ew[s][0] = ld4nc(wq + (G+3)*8);
                    ew[s][1] = ld4nc(wq + (G+3)*8 + 4);
                }
            }
            acc += __shfl_xor(acc, 16); acc += __shfl_xor(acc, 32);
            if (eq == 0) out[(eb*NT + et)*NO + eo] = acc + (float)s_en[w]*bo;
        }
        // ---- per-quad state ----
        int ex[4], md[4], tt[4], sl[4];
        #pragma unroll
        for (int r = 0; r < 4; ++r) {
            const int rr = rq*4 + r;
            ex[r] = s_run[rr]; md[r] = s_mode[rr]; tt[r] = s_t[rr]; sl[r] = s_sl[rr];
        }
        // ---- x-part for rows starting a timestep (L2-warm wihT/x) ----
        #pragma unroll
        for (int r = 0; r < 4; ++r) {
            if (ex[r] && md[r] == 0) {
                float o0 = bias0, o1 = bias1;
                const float* xr = x + ((b0+r)*NT + tt[r])*NI + ks*32;
                const float* wp = wihT + (ks*32)*NH + jg;
                #pragma unroll 4
                for (int i = 0; i < 32; i += 4) {
                    const float4 xv = *(const float4*)(xr + i);
                    const float2 wa = *(const float2*)(wp + (i  )*NH);
                    const float2 wb = *(const float2*)(wp + (i+1)*NH);
                    const float2 wc = *(const float2*)(wp + (i+2)*NH);
                    const float2 wd = *(const float2*)(wp + (i+3)*NH);
                    o0 += xv.x*wa.x + xv.y*wb.x + xv.z*wc.x + xv.w*wd.x;
                    o1 += xv.x*wa.y + xv.y*wb.y + xv.z*wc.y + xv.w*wd.y;
                }
                xw[r][0] = o0; xw[r][1] = o1;
            }
        }
        // ---- staging source for my staged row (replicated state -> uniform) ----
        const float* hsrc;
        {
            const int rn = s_run[row_s], rm = s_mode[row_s];
            const int rt = s_t[row_s],  rs = s_sl[row_s];
            const int b  = gp*16 + row_s;
            if (!rn)           hsrc = hbuf + (b*2)*NH;
            else if (rm == 0)  hsrc = (rt == 0) ? s0 + b*NH
                                      : habuf + ((rt-1)&1)*(NB*NH) + b*NH;
            else               hsrc = hbuf + (b*2 + rs)*NH;
        }
        const float* gbase = hsrc + m_s*64 + t4_s*4;
        // ---- a[] init ----
        #pragma unroll
        for (int r = 0; r < 4; ++r) {
            a[r][0] = xw[r][0] + (md[r] == 0 ? w0a : 0.0f);
            a[r][1] = xw[r][1] + (md[r] == 0 ? w0b : 0.0f);
        }
        // ---- 4-pass staged hh matvec (pipelined: load p+1 under consume p) ----
        vdrain();
        float4 fA = ld4cc(gbase);
        float4 fB;
        // pass 0
        WAITV(0); __syncthreads();
        *(float4*)(&s_hst[dstoff]) = fA;
        fB = ld4cc(gbase + 16);
        __syncthreads();
        consume(0);
        // pass 1
        WAITV(0); __syncthreads();
        *(float4*)(&s_hst[dstoff]) = fB;
        fA = ld4cc(gbase + 32);
        __syncthreads();
        consume(1);
        // pass 2
        WAITV(0); __syncthreads();
        *(float4*)(&s_hst[dstoff]) = fA;
        fB = ld4cc(gbase + 48);
        __syncthreads();
        consume(2);
        // pass 3
        WAITV(0); __syncthreads();
        *(float4*)(&s_hst[dstoff]) = fB;
        __syncthreads();
        consume(3);
        // ---- fold: every lane gets full dots for its col pair ----
        #pragma unroll
        for (int r = 0; r < 4; ++r)
            #pragma unroll
            for (int c = 0; c < 2; ++c) {
                float v = a[r][c];
                v += __shfl_xor(v, 4);  v += __shfl_xor(v, 8);
                v += __shfl_xor(v, 16); v += __shfl_xor(v, 32);
                a[r][c] = v;
            }
        // ---- k0 lanes: tanh, publish h, halt-dot partials ----
        if (k0) {
            #pragma unroll
            for (int r = 0; r < 4; ++r) {
                float ph = 0.0f;
                if (ex[r]) {
                    const float ha = tanhf(a[r][0]), hb = tanhf(a[r][1]);
                    const int b = b0 + r;
                    st2cc(hbuf + (b*2 + (sl[r]^1))*NH + jg, ha, hb);
                    if (md[r] == 0) { hacc[r][0] = ha;  hacc[r][1] = hb; }
                    else            { hacc[r][0] += ha; hacc[r][1] += hb; }
                    st2cc(habuf + (tt[r]&1)*(NB*NH) + b*NH + jg,
                          hacc[r][0], hacc[r][1]);
                    ph = wh0*ha + wh1*hb;
                }
                // fold the 4 up-lanes (0..3) -> wave's 8-col partial
                ph += __shfl_xor(ph, 1);
                ph += __shfl_xor(ph, 2);
                if (up == 0) s_pp[rq*4 + r][co] = ph;
            }
        }
        __syncthreads();
        // one lane per row: block's 32-col partial -> pbuf (fixed order)
        if (lane == 0) {
            const float s4 = ((s_pp[w][0] + s_pp[w][1]) + s_pp[w][2]) + s_pp[w][3];
            st1cc(pbuf + (gp*16 + w)*32 + lb, s4);
        }
        // ================= barrier (RMW-free slot barrier) =================
        ++gen; group_barrier(ctr, gen, lb, tid);
        // ====== p from partials (fixed tree, bit-identical across blocks) ======
        const int exw = s_run[w];
        float p = 0.0f;
        {
            const float* pb = pbuf + (gp*16 + w)*32 + (lane & 7)*4;
            float4 pv = ld4cc(pb);
            WAITV(0);
            float ps = ((pv.x + pv.y) + pv.z) + pv.w;
            ps += __shfl_xor(ps, 1);
            ps += __shfl_xor(ps, 2);
            ps += __shfl_xor(ps, 4);
            if (exw) p = 1.0f/(1.0f + expf(-(ps + bh)));
        }
        // ====== state update (row w, lane 0, replicated deterministic) ======
        if (lane == 0) {
            int newepi = 0;
            if (exw) {
                const int t = s_t[w];
                float cum; int n;
                if (s_mode[w] == 0) {
                    cum = p; n = 1;
                    if (lb == 0) out[PONDOFF + (gp*16 + w)*NT + t] = (p >= 0.99f) ? 2.0f : 0.0f;
                } else {
                    cum = s_cum[w] + p; n = s_n[w] + 1;
                }
                s_cum[w] = cum; s_n[w] = n;
                s_sl[w] ^= 1;
                if ((cum < 0.99f) && n < 12) {
                    s_mode[w] = 1;
                } else {                     // timestep finished
                    newepi = 1; s_et[w] = t; s_en[w] = n;
                    if (t == NT-1) s_run[w] = 0;
                    else { s_t[w] = t + 1; s_mode[w] = 0; }
                }
            }
            s_epi[w] = newepi;
        }
        __syncthreads();
        // alive check: every wave computes it from LDS (uniform result)
        const int al = (lane < 16) ? (s_run[lane] | s_epi[lane]) : 0;
        if (__ballot(al) == 0ULL) break;
    }
}

extern "C" void kernel_launch(void* const* d_in, const int* in_sizes, int n_in,
                              void* d_out, int out_size, void* d_ws, size_t ws_size,
                              hipStream_t stream) {
    const float* x      = (const float*)d_in[0];
    const float* s0     = (const float*)d_in[1];
    const float* w_ih   = (const float*)d_in[2];
    const float* w_hh   = (const float*)d_in[3];
    const float* b_ih   = (const float*)d_in[4];
    const float* b_hh   = (const float*)d_in[5];
    const float* w_halt = (const float*)d_in[6];
    const float* b_halt = (const float*)d_in[7];
    const float* w_out  = (const float*)d_in[8];
    const float* b_out  = (const float*)d_in[9];
    float* out = (float*)d_out;
    float* ws  = (float*)d_ws;

    static const int kLds = 131072;
    (void)hipFuncSetAttribute((const void*)arnn_coop,
                              hipFuncAttributeMaxDynamicSharedMemorySize, kLds);

    void* args[] = { (void*)&x, (void*)&s0, (void*)&w_ih, (void*)&w_hh,
                     (void*)&b_ih, (void*)&b_hh, (void*)&w_halt, (void*)&b_halt,
                     (void*)&w_out, (void*)&b_out, (void*)&out, (void*)&ws };
    (void)hipLaunchCooperativeKernel((void*)arnn_coop, dim3(256), dim3(1024),
                                     args, kLds, stream);
}